// Round 14
// baseline (407.245 us; speedup 1.0000x reference)
//
#include <hip/hip_runtime.h>
#include <hip/hip_fp16.h>

#define N_NODES 100000
#define IN_CH 16
#define HIDDEN 32
#define NUM_HH 1000

#define NPB 128                            // nodes per bucket
#define NBUCK ((N_NODES + NPB - 1) / NPB)  // 782
#define NCHUNK 1024                        // edge chunks (passAB blocks)
#define CAP 4480  // bucket region capacity: mean 4092, sigma 64 -> +6 sigma

// ---------------------------------------------------------------------------
// Fused partition (proven round 7-13): per-chunk LDS histogram -> one global
// atomicAdd per (block,bucket) reserves a contiguous range in the bucket's
// fixed-CAP region -> scatter packed (src | local<<17) into the private range.
// NCHUNK=1024: 4 blocks/CU (vs 2 at 512) doubles latency-hiding waves on
// this atomic/latency-bound kernel; per-block fixed overhead (hist zero +
// 782 reservations) stays ~1/3 of edge work (was ~1:1 at 2048).
// ---------------------------------------------------------------------------
__global__ __launch_bounds__(256) void passAB(
    const int* __restrict__ src, const int* __restrict__ dst,
    int* __restrict__ gcur, unsigned* __restrict__ packed, int n_edges,
    int cepb) {
  __shared__ int hist[NBUCK];
  __shared__ int rbase[NBUCK];
  __shared__ int cur[NBUCK];
  const int tid = threadIdx.x;
  for (int i = tid; i < NBUCK; i += 256) {
    hist[i] = 0;
    cur[i] = 0;
  }
  __syncthreads();

  const int s = blockIdx.x * cepb;
  const int e = min(n_edges, s + cepb);
  for (int i = s + tid; i < e; i += 256) atomicAdd(&hist[dst[i] >> 7], 1);
  __syncthreads();

  for (int b = tid; b < NBUCK; b += 256) {
    const int h = hist[b];
    rbase[b] = h ? atomicAdd(&gcur[b], h) : 0;
  }
  __syncthreads();

  for (int i = s + tid; i < e; i += 256) {
    const int d = dst[i];
    const int b = d >> 7;
    const int off = atomicAdd(&cur[b], 1);
    const int pos = rbase[b] + off;
    if (pos < CAP)  // 6-sigma margin; never taken on this data
      packed[(size_t)b * CAP + pos] =
          (unsigned)src[i] | ((unsigned)(d & (NPB - 1)) << 17);
  }
}

// ---------------------------------------------------------------------------
// Fused bucket-sort + SAGE layer 1 (proven round 10/13). One block per
// bucket. Sort: stage packed in LDS, 128-bin counting sort -> sorted s_adj
// (LDS), write sorted adjacency back to packed (for layer 2) + row_ptr.
// Layer 1 (fp32 x): 4 lanes/edge, 16 edges/wave-iter, shfl_xor butterfly,
// in-wave GEMV relu(mean@w_l + x@w_r + b) -> h1 (fp16).
// ---------------------------------------------------------------------------
__global__ __launch_bounds__(512) void sort_sage1(
    unsigned* __restrict__ packed, const int* __restrict__ gcur,
    int* __restrict__ row_ptr, const float* __restrict__ feat,
    const float* __restrict__ w_l, const float* __restrict__ w_r,
    const float* __restrict__ bias, __half* __restrict__ out) {
  constexpr int CH = IN_CH;    // 16
  constexpr int Q = CH / 4;    // 4 lanes per edge row
  constexpr int EPW = 64 / Q;  // 16 edges per wave iteration
  __shared__ unsigned stage[CAP];
  __shared__ unsigned s_adj[CAP];
  __shared__ int bins[NPB];
  __shared__ int scn[NPB];
  __shared__ int cur[NPB];
  __shared__ float wl[CH * HIDDEN];
  __shared__ float wr[CH * HIDDEN];
  __shared__ float bs[HIDDEN];
  __shared__ float mean_s[8][CH];
  __shared__ float xs[8][CH];

  const int tid = threadIdx.x;
  const int bk = blockIdx.x;
  const int base = bk * NPB;
  const int gbase = bk * CAP;
  const int cnt = min(gcur[bk], CAP);

  for (int i = tid; i < CH * HIDDEN; i += 512) {
    wl[i] = w_l[i];
    wr[i] = w_r[i];
  }
  if (tid < HIDDEN) bs[tid] = bias[tid];
  if (tid < NPB) bins[tid] = 0;
  __syncthreads();

  for (int i = tid; i < cnt; i += 512) {
    const unsigned pk = packed[gbase + i];
    stage[i] = pk;
    atomicAdd(&bins[pk >> 17], 1);
  }
  __syncthreads();
  if (tid < NPB) scn[tid] = bins[tid];
  __syncthreads();
  for (int off = 1; off < NPB; off <<= 1) {
    int t = (tid < NPB && tid >= off) ? scn[tid - off] : 0;
    __syncthreads();
    if (tid < NPB) scn[tid] += t;
    __syncthreads();
  }
  if (tid < NPB) {
    const int excl = scn[tid] - bins[tid];
    cur[tid] = excl;
    const int node = base + tid;
    if (node < N_NODES) row_ptr[node] = gbase + excl;
  }
  if (bk == NBUCK - 1 && tid == 0) row_ptr[N_NODES] = gbase + cnt;
  __syncthreads();
  for (int i = tid; i < cnt; i += 512) {
    const unsigned pk = stage[i];
    const int pos = atomicAdd(&cur[pk >> 17], 1);
    s_adj[pos] = pk & 0x1FFFFu;  // sorted, local bits stripped
  }
  __syncthreads();

  // write sorted adjacency back (fire-and-forget; drains under compute)
  for (int i = tid; i < cnt; i += 512) packed[gbase + i] = s_adj[i];

  // ---- layer-1 compute straight from LDS ----
  const int wave = tid >> 6;
  const int lane = tid & 63;
  const int q = lane & (Q - 1);
  const int esub = lane / Q;
  const int j = lane & 31;
  const int p = lane >> 5;

#pragma unroll 1
  for (int pass = 0; pass < NPB / 8; ++pass) {
    const int l = pass * 8 + wave;  // local node index in bucket
    const int n = base + l;
    if (n < N_NODES) {  // wave-uniform guard
      const int s = scn[l] - bins[l];
      const int e = scn[l];

      // hoist own-feature load ahead of the gather loop
      float4 xv = {0.f, 0.f, 0.f, 0.f};
      if (esub == 0) xv = ((const float4*)(feat + (size_t)n * CH))[q];

      float4 acc = {0.f, 0.f, 0.f, 0.f};
      for (int i = s + esub; i < e; i += EPW) {
        const int sn = (int)s_adj[i];
        const float4 v = ((const float4*)(feat + (size_t)sn * CH))[q];
        acc.x += v.x;
        acc.y += v.y;
        acc.z += v.z;
        acc.w += v.w;
      }
#pragma unroll
      for (int m = Q; m < 64; m <<= 1) {
        acc.x += __shfl_xor(acc.x, m, 64);
        acc.y += __shfl_xor(acc.y, m, 64);
        acc.z += __shfl_xor(acc.z, m, 64);
        acc.w += __shfl_xor(acc.w, m, 64);
      }
      const float inv = 1.0f / fmaxf((float)(e - s), 1.0f);
      if (esub == 0) {  // lane == q
        mean_s[wave][4 * q + 0] = acc.x * inv;
        mean_s[wave][4 * q + 1] = acc.y * inv;
        mean_s[wave][4 * q + 2] = acc.z * inv;
        mean_s[wave][4 * q + 3] = acc.w * inv;
        xs[wave][4 * q + 0] = xv.x;
        xs[wave][4 * q + 1] = xv.y;
        xs[wave][4 * q + 2] = xv.z;
        xs[wave][4 * q + 3] = xv.w;
      }
      __builtin_amdgcn_wave_barrier();  // intra-wave LDS RAW

      float o = 0.f;
#pragma unroll
      for (int k = p * (CH / 2); k < (p + 1) * (CH / 2); ++k)
        o = fmaf(mean_s[wave][k], wl[k * HIDDEN + j],
                 fmaf(xs[wave][k], wr[k * HIDDEN + j], o));
      o += __shfl_xor(o, 32, 64);
      if (p == 0)
        out[(size_t)n * HIDDEN + j] = __float2half(fmaxf(o + bs[j], 0.f));
      __builtin_amdgcn_wave_barrier();
    }
  }
}

// ---------------------------------------------------------------------------
// SAGE layer 2 over FP16 h1 (proven round 10/13). One block per bucket.
// Row = 32 halfs = 64 B = 4x 16B quads; 4 lanes/edge, 16 edges/wave-iter.
// fp32 accumulate; output h2 fp32.
// ---------------------------------------------------------------------------
__global__ __launch_bounds__(512) void sage2(
    const __half* __restrict__ feat, const int* __restrict__ row_ptr,
    const unsigned* __restrict__ adj, const int* __restrict__ gcur,
    const float* __restrict__ w_l, const float* __restrict__ w_r,
    const float* __restrict__ bias, float* __restrict__ out) {
  constexpr int CH = HIDDEN;  // 32
  constexpr int Q = 4;        // 16B quads per 64B row
  constexpr int EPW = 16;     // edges per wave iteration
  __shared__ unsigned s_adj[CAP];
  __shared__ float wl[CH * HIDDEN];
  __shared__ float wr[CH * HIDDEN];
  __shared__ float bs[HIDDEN];
  __shared__ float mean_s[8][CH];
  __shared__ float xs[8][CH];

  const int tid = threadIdx.x;
  const int bk = blockIdx.x;
  const int base = bk * NPB;
  const int gbase = bk * CAP;
  const int bcnt = min(gcur[bk], CAP);

  for (int i = tid; i < CH * HIDDEN; i += 512) {
    wl[i] = w_l[i];
    wr[i] = w_r[i];
  }
  if (tid < HIDDEN) bs[tid] = bias[tid];
  for (int i = tid; i < bcnt; i += 512) s_adj[i] = adj[gbase + i];
  __syncthreads();

  const int wave = tid >> 6;
  const int lane = tid & 63;
  const int q = lane & 3;      // quad in row
  const int esub = lane >> 2;  // 0..15
  const int j = lane & 31;
  const int p = lane >> 5;

#pragma unroll 1
  for (int pass = 0; pass < NPB / 8; ++pass) {
    const int l = pass * 8 + wave;
    const int n = base + l;
    if (n < N_NODES) {
      const int s = row_ptr[n] - gbase;
      const int e = (l == NPB - 1) ? bcnt : row_ptr[n + 1] - gbase;

      // hoist own-feature quad (8 halfs) ahead of gather loop
      uint4 xu = {0, 0, 0, 0};
      if (esub == 0) xu = ((const uint4*)(feat + (size_t)n * CH))[q];

      float acc[8] = {0.f, 0.f, 0.f, 0.f, 0.f, 0.f, 0.f, 0.f};
#pragma unroll 2
      for (int i = s + esub; i < e; i += EPW) {
        const int sn = (int)s_adj[i];
        union {
          uint4 u;
          __half2 h[4];
        } U;
        U.u = ((const uint4*)(feat + (size_t)sn * CH))[q];
#pragma unroll
        for (int t = 0; t < 4; ++t) {
          const float2 f = __half22float2(U.h[t]);
          acc[2 * t] += f.x;
          acc[2 * t + 1] += f.y;
        }
      }
#pragma unroll
      for (int m = Q; m < 64; m <<= 1) {
#pragma unroll
        for (int t = 0; t < 8; ++t) acc[t] += __shfl_xor(acc[t], m, 64);
      }
      const float inv = 1.0f / fmaxf((float)(e - s), 1.0f);
      if (esub == 0) {  // lanes 0..3, q = lane
#pragma unroll
        for (int t = 0; t < 8; ++t) mean_s[wave][8 * q + t] = acc[t] * inv;
        union {
          uint4 u;
          __half2 h[4];
        } X;
        X.u = xu;
#pragma unroll
        for (int t = 0; t < 4; ++t) {
          const float2 f = __half22float2(X.h[t]);
          xs[wave][8 * q + 2 * t] = f.x;
          xs[wave][8 * q + 2 * t + 1] = f.y;
        }
      }
      __builtin_amdgcn_wave_barrier();  // intra-wave LDS RAW

      float o = 0.f;
#pragma unroll
      for (int k = p * (CH / 2); k < (p + 1) * (CH / 2); ++k)
        o = fmaf(mean_s[wave][k], wl[k * HIDDEN + j],
                 fmaf(xs[wave][k], wr[k * HIDDEN + j], o));
      o += __shfl_xor(o, 32, 64);
      if (p == 0) out[(size_t)n * HIDDEN + j] = fmaxf(o + bs[j], 0.f);
      __builtin_amdgcn_wave_barrier();
    }
  }
}

// ---------------------------------------------------------------------------
// FC head, LDS-free + NON-TEMPORAL stores (proven round 13): the 400 MB
// output is written once and never re-read, so bypass L2 write-allocate.
// 256 threads / 128-node tile; 4 columns/thread, 32 weights each in VGPRs;
// h rows read via WAVE-UNIFORM global float4 broadcasts; coalesced stores.
// ---------------------------------------------------------------------------
#define FC_BN 128
__global__ __launch_bounds__(256) void fc_direct(
    const float* __restrict__ h, const float* __restrict__ fcw,
    const float* __restrict__ fcb, float* __restrict__ out) {
  const int tid = threadIdx.x;
  const int base = blockIdx.x * FC_BN;
  const int nvalid = min(FC_BN, N_NODES - base);

  float w[4][HIDDEN];
  float bias[4];
#pragma unroll
  for (int c = 0; c < 4; ++c) {
    const int j = c * 256 + tid;
    const bool valid = j < NUM_HH;
    bias[c] = valid ? fcb[j] : 0.f;
#pragma unroll
    for (int k = 0; k < HIDDEN; ++k)
      w[c][k] = valid ? fcw[k * NUM_HH + j] : 0.f;
  }

#pragma unroll 2
  for (int n = 0; n < nvalid; ++n) {
    const float4* hrow = (const float4*)(h + (size_t)(base + n) * HIDDEN);
    float a0 = bias[0], a1 = bias[1], a2 = bias[2], a3 = bias[3];
#pragma unroll
    for (int k4 = 0; k4 < HIDDEN / 4; ++k4) {
      const float4 hv = hrow[k4];
      a0 = fmaf(hv.x, w[0][4 * k4 + 0], a0);
      a0 = fmaf(hv.y, w[0][4 * k4 + 1], a0);
      a0 = fmaf(hv.z, w[0][4 * k4 + 2], a0);
      a0 = fmaf(hv.w, w[0][4 * k4 + 3], a0);
      a1 = fmaf(hv.x, w[1][4 * k4 + 0], a1);
      a1 = fmaf(hv.y, w[1][4 * k4 + 1], a1);
      a1 = fmaf(hv.z, w[1][4 * k4 + 2], a1);
      a1 = fmaf(hv.w, w[1][4 * k4 + 3], a1);
      a2 = fmaf(hv.x, w[2][4 * k4 + 0], a2);
      a2 = fmaf(hv.y, w[2][4 * k4 + 1], a2);
      a2 = fmaf(hv.z, w[2][4 * k4 + 2], a2);
      a2 = fmaf(hv.w, w[2][4 * k4 + 3], a2);
      a3 = fmaf(hv.x, w[3][4 * k4 + 0], a3);
      a3 = fmaf(hv.y, w[3][4 * k4 + 1], a3);
      a3 = fmaf(hv.z, w[3][4 * k4 + 2], a3);
      a3 = fmaf(hv.w, w[3][4 * k4 + 3], a3);
    }
    float* orow = out + (size_t)(base + n) * NUM_HH;
    __builtin_nontemporal_store(a0, orow + tid);
    __builtin_nontemporal_store(a1, orow + 256 + tid);
    __builtin_nontemporal_store(a2, orow + 512 + tid);
    if (768 + tid < NUM_HH)
      __builtin_nontemporal_store(a3, orow + 768 + tid);
  }
}

extern "C" void kernel_launch(void* const* d_in, const int* in_sizes, int n_in,
                              void* d_out, int out_size, void* d_ws,
                              size_t ws_size, hipStream_t stream) {
  const float* x = (const float*)d_in[0];
  const int* edge = (const int*)d_in[1];
  const float* w1_l = (const float*)d_in[2];
  const float* w1_r = (const float*)d_in[3];
  const float* b1 = (const float*)d_in[4];
  const float* w2_l = (const float*)d_in[5];
  const float* w2_r = (const float*)d_in[6];
  const float* b2 = (const float*)d_in[7];
  const float* fc_w = (const float*)d_in[8];
  const float* fc_b = (const float*)d_in[9];
  float* out = (float*)d_out;

  const int n_edges = in_sizes[1] / 2;
  const int* src = edge;
  const int* dst = edge + n_edges;

  // Workspace (~33.6 MB): packed[NBUCK*CAP] | h1 half[N*32] | h2 f32[N*32]
  //                       | gcur[NBUCK] | row_ptr[N+1]
  unsigned* packed = (unsigned*)d_ws;
  __half* h1 = (__half*)(packed + (size_t)NBUCK * CAP);
  float* h2 = (float*)(h1 + (size_t)N_NODES * HIDDEN);
  int* gcur = (int*)(h2 + (size_t)N_NODES * HIDDEN);
  int* row_ptr = gcur + NBUCK;

  const int cepb = (n_edges + NCHUNK - 1) / NCHUNK;
  const int fgrid = (N_NODES + FC_BN - 1) / FC_BN;

  // ---- partition ----
  hipMemsetAsync(gcur, 0, NBUCK * sizeof(int), stream);
  passAB<<<NCHUNK, 256, 0, stream>>>(src, dst, gcur, packed, n_edges, cepb);

  // ---- bucket sort + layer 1 fused: x -> h1 (fp16), sorted adj -> packed
  sort_sage1<<<NBUCK, 512, 0, stream>>>(packed, gcur, row_ptr, x, w1_l, w1_r,
                                        b1, h1);

  // ---- layer 2 (fp16 gather): h1 -> h2 ----
  sage2<<<NBUCK, 512, 0, stream>>>(h1, row_ptr, packed, gcur, w2_l, w2_r, b2,
                                   h2);

  // ---- FC head (standalone, register-resident weights, NT stores) ----
  fc_direct<<<fgrid, 256, 0, stream>>>(h2, fc_w, fc_b, out);
}

// Round 15
// 388.572 us; speedup vs baseline: 1.0481x; 1.0481x over previous
//
#include <hip/hip_runtime.h>
#include <hip/hip_fp16.h>

#define N_NODES 100000
#define IN_CH 16
#define HIDDEN 32
#define NUM_HH 1000

#define NPB 128                            // nodes per bucket
#define NBUCK ((N_NODES + NPB - 1) / NPB)  // 782
#define NCHUNK 512                         // edge chunks (passAB blocks) — measured optimum (512 > 1024 > 2048)
#define CAP 4480  // bucket region capacity: mean 4092, sigma 64 -> +6 sigma

// ---------------------------------------------------------------------------
// Fused partition (proven rounds 7-13): per-chunk LDS histogram -> one global
// atomicAdd per (block,bucket) reserves a contiguous range in the bucket's
// fixed-CAP region -> scatter packed (src | local<<17) into the private range.
// NCHUNK=512 measured optimal: kernel is reservation-overhead-bound, not
// wave-starved (1024 cost +17 us, 2048 worse).
// ---------------------------------------------------------------------------
__global__ __launch_bounds__(256) void passAB(
    const int* __restrict__ src, const int* __restrict__ dst,
    int* __restrict__ gcur, unsigned* __restrict__ packed, int n_edges,
    int cepb) {
  __shared__ int hist[NBUCK];
  __shared__ int rbase[NBUCK];
  __shared__ int cur[NBUCK];
  const int tid = threadIdx.x;
  for (int i = tid; i < NBUCK; i += 256) {
    hist[i] = 0;
    cur[i] = 0;
  }
  __syncthreads();

  const int s = blockIdx.x * cepb;
  const int e = min(n_edges, s + cepb);
  for (int i = s + tid; i < e; i += 256) atomicAdd(&hist[dst[i] >> 7], 1);
  __syncthreads();

  for (int b = tid; b < NBUCK; b += 256) {
    const int h = hist[b];
    rbase[b] = h ? atomicAdd(&gcur[b], h) : 0;
  }
  __syncthreads();

  for (int i = s + tid; i < e; i += 256) {
    const int d = dst[i];
    const int b = d >> 7;
    const int off = atomicAdd(&cur[b], 1);
    const int pos = rbase[b] + off;
    if (pos < CAP)  // 6-sigma margin; never taken on this data
      packed[(size_t)b * CAP + pos] =
          (unsigned)src[i] | ((unsigned)(d & (NPB - 1)) << 17);
  }
}

// ---------------------------------------------------------------------------
// Fused bucket-sort + SAGE layer 1 (proven rounds 10/13). One block per
// bucket. Sort: stage packed in LDS, 128-bin counting sort -> sorted s_adj
// (LDS), write sorted adjacency back to packed (for layer 2) + row_ptr.
// Layer 1 (fp32 x): 4 lanes/edge, 16 edges/wave-iter, shfl_xor butterfly,
// in-wave GEMV relu(mean@w_l + x@w_r + b) -> h1 (fp16).
// ---------------------------------------------------------------------------
__global__ __launch_bounds__(512) void sort_sage1(
    unsigned* __restrict__ packed, const int* __restrict__ gcur,
    int* __restrict__ row_ptr, const float* __restrict__ feat,
    const float* __restrict__ w_l, const float* __restrict__ w_r,
    const float* __restrict__ bias, __half* __restrict__ out) {
  constexpr int CH = IN_CH;    // 16
  constexpr int Q = CH / 4;    // 4 lanes per edge row
  constexpr int EPW = 64 / Q;  // 16 edges per wave iteration
  __shared__ unsigned stage[CAP];
  __shared__ unsigned s_adj[CAP];
  __shared__ int bins[NPB];
  __shared__ int scn[NPB];
  __shared__ int cur[NPB];
  __shared__ float wl[CH * HIDDEN];
  __shared__ float wr[CH * HIDDEN];
  __shared__ float bs[HIDDEN];
  __shared__ float mean_s[8][CH];
  __shared__ float xs[8][CH];

  const int tid = threadIdx.x;
  const int bk = blockIdx.x;
  const int base = bk * NPB;
  const int gbase = bk * CAP;
  const int cnt = min(gcur[bk], CAP);

  for (int i = tid; i < CH * HIDDEN; i += 512) {
    wl[i] = w_l[i];
    wr[i] = w_r[i];
  }
  if (tid < HIDDEN) bs[tid] = bias[tid];
  if (tid < NPB) bins[tid] = 0;
  __syncthreads();

  for (int i = tid; i < cnt; i += 512) {
    const unsigned pk = packed[gbase + i];
    stage[i] = pk;
    atomicAdd(&bins[pk >> 17], 1);
  }
  __syncthreads();
  if (tid < NPB) scn[tid] = bins[tid];
  __syncthreads();
  for (int off = 1; off < NPB; off <<= 1) {
    int t = (tid < NPB && tid >= off) ? scn[tid - off] : 0;
    __syncthreads();
    if (tid < NPB) scn[tid] += t;
    __syncthreads();
  }
  if (tid < NPB) {
    const int excl = scn[tid] - bins[tid];
    cur[tid] = excl;
    const int node = base + tid;
    if (node < N_NODES) row_ptr[node] = gbase + excl;
  }
  if (bk == NBUCK - 1 && tid == 0) row_ptr[N_NODES] = gbase + cnt;
  __syncthreads();
  for (int i = tid; i < cnt; i += 512) {
    const unsigned pk = stage[i];
    const int pos = atomicAdd(&cur[pk >> 17], 1);
    s_adj[pos] = pk & 0x1FFFFu;  // sorted, local bits stripped
  }
  __syncthreads();

  // write sorted adjacency back (fire-and-forget; drains under compute)
  for (int i = tid; i < cnt; i += 512) packed[gbase + i] = s_adj[i];

  // ---- layer-1 compute straight from LDS ----
  const int wave = tid >> 6;
  const int lane = tid & 63;
  const int q = lane & (Q - 1);
  const int esub = lane / Q;
  const int j = lane & 31;
  const int p = lane >> 5;

#pragma unroll 1
  for (int pass = 0; pass < NPB / 8; ++pass) {
    const int l = pass * 8 + wave;  // local node index in bucket
    const int n = base + l;
    if (n < N_NODES) {  // wave-uniform guard
      const int s = scn[l] - bins[l];
      const int e = scn[l];

      // hoist own-feature load ahead of the gather loop
      float4 xv = {0.f, 0.f, 0.f, 0.f};
      if (esub == 0) xv = ((const float4*)(feat + (size_t)n * CH))[q];

      float4 acc = {0.f, 0.f, 0.f, 0.f};
      for (int i = s + esub; i < e; i += EPW) {
        const int sn = (int)s_adj[i];
        const float4 v = ((const float4*)(feat + (size_t)sn * CH))[q];
        acc.x += v.x;
        acc.y += v.y;
        acc.z += v.z;
        acc.w += v.w;
      }
#pragma unroll
      for (int m = Q; m < 64; m <<= 1) {
        acc.x += __shfl_xor(acc.x, m, 64);
        acc.y += __shfl_xor(acc.y, m, 64);
        acc.z += __shfl_xor(acc.z, m, 64);
        acc.w += __shfl_xor(acc.w, m, 64);
      }
      const float inv = 1.0f / fmaxf((float)(e - s), 1.0f);
      if (esub == 0) {  // lane == q
        mean_s[wave][4 * q + 0] = acc.x * inv;
        mean_s[wave][4 * q + 1] = acc.y * inv;
        mean_s[wave][4 * q + 2] = acc.z * inv;
        mean_s[wave][4 * q + 3] = acc.w * inv;
        xs[wave][4 * q + 0] = xv.x;
        xs[wave][4 * q + 1] = xv.y;
        xs[wave][4 * q + 2] = xv.z;
        xs[wave][4 * q + 3] = xv.w;
      }
      __builtin_amdgcn_wave_barrier();  // intra-wave LDS RAW

      float o = 0.f;
#pragma unroll
      for (int k = p * (CH / 2); k < (p + 1) * (CH / 2); ++k)
        o = fmaf(mean_s[wave][k], wl[k * HIDDEN + j],
                 fmaf(xs[wave][k], wr[k * HIDDEN + j], o));
      o += __shfl_xor(o, 32, 64);
      if (p == 0)
        out[(size_t)n * HIDDEN + j] = __float2half(fmaxf(o + bs[j], 0.f));
      __builtin_amdgcn_wave_barrier();
    }
  }
}

// ---------------------------------------------------------------------------
// SAGE layer 2 over FP16 h1 (proven rounds 10/13). One block per bucket.
// Row = 32 halfs = 64 B = 4x 16B quads; 4 lanes/edge, 16 edges/wave-iter.
// fp32 accumulate; output h2 fp32.
// ---------------------------------------------------------------------------
__global__ __launch_bounds__(512) void sage2(
    const __half* __restrict__ feat, const int* __restrict__ row_ptr,
    const unsigned* __restrict__ adj, const int* __restrict__ gcur,
    const float* __restrict__ w_l, const float* __restrict__ w_r,
    const float* __restrict__ bias, float* __restrict__ out) {
  constexpr int CH = HIDDEN;  // 32
  constexpr int Q = 4;        // 16B quads per 64B row
  constexpr int EPW = 16;     // edges per wave iteration
  __shared__ unsigned s_adj[CAP];
  __shared__ float wl[CH * HIDDEN];
  __shared__ float wr[CH * HIDDEN];
  __shared__ float bs[HIDDEN];
  __shared__ float mean_s[8][CH];
  __shared__ float xs[8][CH];

  const int tid = threadIdx.x;
  const int bk = blockIdx.x;
  const int base = bk * NPB;
  const int gbase = bk * CAP;
  const int bcnt = min(gcur[bk], CAP);

  for (int i = tid; i < CH * HIDDEN; i += 512) {
    wl[i] = w_l[i];
    wr[i] = w_r[i];
  }
  if (tid < HIDDEN) bs[tid] = bias[tid];
  for (int i = tid; i < bcnt; i += 512) s_adj[i] = adj[gbase + i];
  __syncthreads();

  const int wave = tid >> 6;
  const int lane = tid & 63;
  const int q = lane & 3;      // quad in row
  const int esub = lane >> 2;  // 0..15
  const int j = lane & 31;
  const int p = lane >> 5;

#pragma unroll 1
  for (int pass = 0; pass < NPB / 8; ++pass) {
    const int l = pass * 8 + wave;
    const int n = base + l;
    if (n < N_NODES) {
      const int s = row_ptr[n] - gbase;
      const int e = (l == NPB - 1) ? bcnt : row_ptr[n + 1] - gbase;

      // hoist own-feature quad (8 halfs) ahead of gather loop
      uint4 xu = {0, 0, 0, 0};
      if (esub == 0) xu = ((const uint4*)(feat + (size_t)n * CH))[q];

      float acc[8] = {0.f, 0.f, 0.f, 0.f, 0.f, 0.f, 0.f, 0.f};
#pragma unroll 2
      for (int i = s + esub; i < e; i += EPW) {
        const int sn = (int)s_adj[i];
        union {
          uint4 u;
          __half2 h[4];
        } U;
        U.u = ((const uint4*)(feat + (size_t)sn * CH))[q];
#pragma unroll
        for (int t = 0; t < 4; ++t) {
          const float2 f = __half22float2(U.h[t]);
          acc[2 * t] += f.x;
          acc[2 * t + 1] += f.y;
        }
      }
#pragma unroll
      for (int m = Q; m < 64; m <<= 1) {
#pragma unroll
        for (int t = 0; t < 8; ++t) acc[t] += __shfl_xor(acc[t], m, 64);
      }
      const float inv = 1.0f / fmaxf((float)(e - s), 1.0f);
      if (esub == 0) {  // lanes 0..3, q = lane
#pragma unroll
        for (int t = 0; t < 8; ++t) mean_s[wave][8 * q + t] = acc[t] * inv;
        union {
          uint4 u;
          __half2 h[4];
        } X;
        X.u = xu;
#pragma unroll
        for (int t = 0; t < 4; ++t) {
          const float2 f = __half22float2(X.h[t]);
          xs[wave][8 * q + 2 * t] = f.x;
          xs[wave][8 * q + 2 * t + 1] = f.y;
        }
      }
      __builtin_amdgcn_wave_barrier();  // intra-wave LDS RAW

      float o = 0.f;
#pragma unroll
      for (int k = p * (CH / 2); k < (p + 1) * (CH / 2); ++k)
        o = fmaf(mean_s[wave][k], wl[k * HIDDEN + j],
                 fmaf(xs[wave][k], wr[k * HIDDEN + j], o));
      o += __shfl_xor(o, 32, 64);
      if (p == 0) out[(size_t)n * HIDDEN + j] = fmaxf(o + bs[j], 0.f);
      __builtin_amdgcn_wave_barrier();
    }
  }
}

// ---------------------------------------------------------------------------
// FC head, LDS-free + NON-TEMPORAL stores (proven round 13): the 400 MB
// output is written once and never re-read, so bypass L2 write-allocate.
// 256 threads / 128-node tile; 4 columns/thread, 32 weights each in VGPRs;
// h rows read via WAVE-UNIFORM global float4 broadcasts; coalesced stores.
// ---------------------------------------------------------------------------
#define FC_BN 128
__global__ __launch_bounds__(256) void fc_direct(
    const float* __restrict__ h, const float* __restrict__ fcw,
    const float* __restrict__ fcb, float* __restrict__ out) {
  const int tid = threadIdx.x;
  const int base = blockIdx.x * FC_BN;
  const int nvalid = min(FC_BN, N_NODES - base);

  float w[4][HIDDEN];
  float bias[4];
#pragma unroll
  for (int c = 0; c < 4; ++c) {
    const int j = c * 256 + tid;
    const bool valid = j < NUM_HH;
    bias[c] = valid ? fcb[j] : 0.f;
#pragma unroll
    for (int k = 0; k < HIDDEN; ++k)
      w[c][k] = valid ? fcw[k * NUM_HH + j] : 0.f;
  }

#pragma unroll 2
  for (int n = 0; n < nvalid; ++n) {
    const float4* hrow = (const float4*)(h + (size_t)(base + n) * HIDDEN);
    float a0 = bias[0], a1 = bias[1], a2 = bias[2], a3 = bias[3];
#pragma unroll
    for (int k4 = 0; k4 < HIDDEN / 4; ++k4) {
      const float4 hv = hrow[k4];
      a0 = fmaf(hv.x, w[0][4 * k4 + 0], a0);
      a0 = fmaf(hv.y, w[0][4 * k4 + 1], a0);
      a0 = fmaf(hv.z, w[0][4 * k4 + 2], a0);
      a0 = fmaf(hv.w, w[0][4 * k4 + 3], a0);
      a1 = fmaf(hv.x, w[1][4 * k4 + 0], a1);
      a1 = fmaf(hv.y, w[1][4 * k4 + 1], a1);
      a1 = fmaf(hv.z, w[1][4 * k4 + 2], a1);
      a1 = fmaf(hv.w, w[1][4 * k4 + 3], a1);
      a2 = fmaf(hv.x, w[2][4 * k4 + 0], a2);
      a2 = fmaf(hv.y, w[2][4 * k4 + 1], a2);
      a2 = fmaf(hv.z, w[2][4 * k4 + 2], a2);
      a2 = fmaf(hv.w, w[2][4 * k4 + 3], a2);
      a3 = fmaf(hv.x, w[3][4 * k4 + 0], a3);
      a3 = fmaf(hv.y, w[3][4 * k4 + 1], a3);
      a3 = fmaf(hv.z, w[3][4 * k4 + 2], a3);
      a3 = fmaf(hv.w, w[3][4 * k4 + 3], a3);
    }
    float* orow = out + (size_t)(base + n) * NUM_HH;
    __builtin_nontemporal_store(a0, orow + tid);
    __builtin_nontemporal_store(a1, orow + 256 + tid);
    __builtin_nontemporal_store(a2, orow + 512 + tid);
    if (768 + tid < NUM_HH)
      __builtin_nontemporal_store(a3, orow + 768 + tid);
  }
}

extern "C" void kernel_launch(void* const* d_in, const int* in_sizes, int n_in,
                              void* d_out, int out_size, void* d_ws,
                              size_t ws_size, hipStream_t stream) {
  const float* x = (const float*)d_in[0];
  const int* edge = (const int*)d_in[1];
  const float* w1_l = (const float*)d_in[2];
  const float* w1_r = (const float*)d_in[3];
  const float* b1 = (const float*)d_in[4];
  const float* w2_l = (const float*)d_in[5];
  const float* w2_r = (const float*)d_in[6];
  const float* b2 = (const float*)d_in[7];
  const float* fc_w = (const float*)d_in[8];
  const float* fc_b = (const float*)d_in[9];
  float* out = (float*)d_out;

  const int n_edges = in_sizes[1] / 2;
  const int* src = edge;
  const int* dst = edge + n_edges;

  // Workspace (~33.6 MB): packed[NBUCK*CAP] | h1 half[N*32] | h2 f32[N*32]
  //                       | gcur[NBUCK] | row_ptr[N+1]
  unsigned* packed = (unsigned*)d_ws;
  __half* h1 = (__half*)(packed + (size_t)NBUCK * CAP);
  float* h2 = (float*)(h1 + (size_t)N_NODES * HIDDEN);
  int* gcur = (int*)(h2 + (size_t)N_NODES * HIDDEN);
  int* row_ptr = gcur + NBUCK;

  const int cepb = (n_edges + NCHUNK - 1) / NCHUNK;
  const int fgrid = (N_NODES + FC_BN - 1) / FC_BN;

  // ---- partition ----
  hipMemsetAsync(gcur, 0, NBUCK * sizeof(int), stream);
  passAB<<<NCHUNK, 256, 0, stream>>>(src, dst, gcur, packed, n_edges, cepb);

  // ---- bucket sort + layer 1 fused: x -> h1 (fp16), sorted adj -> packed
  sort_sage1<<<NBUCK, 512, 0, stream>>>(packed, gcur, row_ptr, x, w1_l, w1_r,
                                        b1, h1);

  // ---- layer 2 (fp16 gather): h1 -> h2 ----
  sage2<<<NBUCK, 512, 0, stream>>>(h1, row_ptr, packed, gcur, w2_l, w2_r, b2,
                                   h2);

  // ---- FC head (standalone, register-resident weights, NT stores) ----
  fc_direct<<<fgrid, 256, 0, stream>>>(h2, fc_w, fc_b, out);
}